// Round 5
// baseline (53.333 us; speedup 1.0000x reference)
//
#include <hip/hip_runtime.h>

#define BC 88                       // B*C channels
#define NVOX 262144                 // 64^3
#define KBINS 20
#define NEDGE 21                    // contiguous bin edges e[0..20]
#define SPLIT 32                    // blocks per channel
#define THREADS 256
#define EPB (NVOX / SPLIT)          // 8192 element-pairs per block
#define V4PT (EPB / (THREADS * 4))  // 8 float4 per thread
#define NBLOCKS (BC * SPLIT)        // 2816
#define ROWW 7                      // LDS fold-row stride in dwords (6 + 1 pad)

// Packed-byte thermometer CDF, fully in VGPRs. c[j] = #(x < e[j]) lives as
// byte j of {H0,H1,H2} (bias 0x80). hist[k] = c[k+1]-c[k]; bias cancels.
// Inner loop has ZERO LDS operations (R1/R2/R4 showed DS pipe = 67us floor).
__global__ void __launch_bounds__(THREADS)
binloss_main(const float* __restrict__ inp, const float* __restrict__ tar,
             const float* __restrict__ br, int* __restrict__ g_cdf,
             float* __restrict__ partials)
{
    __shared__ unsigned int hrows[THREADS * ROWW];  // 7168 B
    __shared__ float wsum[THREADS / 64];

    const int tid = threadIdx.x;

    // uniform scalar loads; affine map with +1 folded so trunc==floor
    const float e0     = br[0];
    const float eK     = br[2 * KBINS - 1];
    const float inv_w  = (float)KBINS / (eK - e0);
    const float shift1 = 1.0f - e0 * inv_w;
    const float tmax   = (float)(KBINS + 1) + 0.5f;   // 21.5

    const int bid = blockIdx.x;
    const int ch  = bid >> 5;                 // / SPLIT
    const int sp  = bid & (SPLIT - 1);
    const size_t base = (size_t)ch * NVOX + (size_t)sp * EPB;
    const float4* ip = (const float4*)(inp + base);
    const float4* tp = (const float4*)(tar + base);

    const unsigned long long ONES = 0x0101010101010101ull;
    const unsigned long long BIAS = 0x8080808080808080ull;
    unsigned long long H0 = BIAS, H1 = BIAS, H2 = BIAS;
    float s_lin = 0.f, s_quad = 0.f;

#pragma unroll
    for (int it = 0; it < V4PT; ++it) {
        float4 a = ip[it * THREADS + tid];
        float4 b = tp[it * THREADS + tid];
#pragma unroll
        for (int q = 0; q < 4; ++q) {
            float av = (&a.x)[q], bv = (&b.x)[q];
            // SmoothL1: [max(d,1)-1] + 0.5*min(d,1)^2 ; the -1 is hoisted out
            float diff = av - bv;
            float ad   = fabsf(diff);
            s_lin += fmaxf(ad, 1.0f);
            float m = fminf(ad, 1.0f);
            s_quad  = __builtin_fmaf(m, m, s_quad);

            // k1 = (#edges <= x) in [0,21]; byte j of T gets +1 iff j >= k1
            float ta = __builtin_amdgcn_fmed3f(__builtin_fmaf(av, inv_w, shift1), 0.0f, tmax);
            float tb = __builtin_amdgcn_fmed3f(__builtin_fmaf(bv, inv_w, shift1), 0.0f, tmax);
            int ka1 = (int)ta;                 // trunc == floor (>=0)
            int kb1 = (int)tb;

            unsigned long long Pa = ONES << ((8 * ka1) & 63);   // pattern reused per word
            unsigned long long Pb = ONES << ((8 * kb1) & 63);

            unsigned long long A0 = (ka1 < 8)  ? Pa : 0ull;
            unsigned long long Ua = (ka1 < 16) ? Pa : 0ull;
            unsigned long long A1 = (ka1 < 8)  ? ONES : Ua;
            unsigned long long A2 = (ka1 < 16) ? ONES : Pa;

            unsigned long long B0 = (kb1 < 8)  ? Pb : 0ull;
            unsigned long long Ub = (kb1 < 16) ? Pb : 0ull;
            unsigned long long B1 = (kb1 < 8)  ? ONES : Ub;
            unsigned long long B2 = (kb1 < 16) ? ONES : Pb;

            H0 += A0; H0 -= B0;    // per-byte |delta| <= 32 around 0x80: no carries
            H1 += A1; H1 -= B1;
            H2 += A2; H2 -= B2;
        }
    }

    // SmoothL1 wave(64) + cross-wave reduce
    float sl1 = (s_lin - (float)(V4PT * 4)) + 0.5f * s_quad;
#pragma unroll
    for (int off = 32; off > 0; off >>= 1) sl1 += __shfl_down(sl1, off, 64);
    if ((tid & 63) == 0) wsum[tid >> 6] = sl1;

    // dump packed CDF rows to LDS for the block fold
    const int rb = tid * ROWW;
    hrows[rb + 0] = (unsigned int)H0; hrows[rb + 1] = (unsigned int)(H0 >> 32);
    hrows[rb + 2] = (unsigned int)H1; hrows[rb + 3] = (unsigned int)(H1 >> 32);
    hrows[rb + 4] = (unsigned int)H2; hrows[rb + 5] = (unsigned int)(H2 >> 32);
    __syncthreads();

    if (tid == 0)
        partials[bid] = wsum[0] + wsum[1] + wsum[2] + wsum[3];

    // fold: 21 edges x 4 quarters; biased sums (bias cancels in c[k+1]-c[k])
    if (tid < NEDGE * 4) {
        const int j = tid % NEDGE, qr = tid / NEDGE;
        const int dw = j >> 2, sh = 8 * (j & 3);
        int s = 0;
#pragma unroll 8
        for (int r = qr * 64; r < qr * 64 + 64; ++r)
            s += (int)((hrows[r * ROWW + dw] >> sh) & 0xFFu);
        atomicAdd(&g_cdf[ch * NEDGE + j], s);
    }
}

__global__ void __launch_bounds__(256)
binloss_final(const int* __restrict__ g_cdf, const float* __restrict__ partials,
              float* __restrict__ out)
{
    __shared__ double r1[256];
    __shared__ double r2[256];
    const int tid = threadIdx.x;
    double s1 = 0.0, s2 = 0.0;
    for (int i = tid; i < NBLOCKS; i += 256) s1 += (double)partials[i];
    for (int i = tid; i < BC * KBINS; i += 256) {
        int ch = i / KBINS, k = i - ch * KBINS;
        int hd = g_cdf[ch * NEDGE + k + 1] - g_cdf[ch * NEDGE + k];  // bias cancels
        s2 += fabs((double)hd);
    }
    r1[tid] = s1; r2[tid] = s2;
    __syncthreads();
    for (int off = 128; off > 0; off >>= 1) {
        if (tid < off) { r1[tid] += r1[tid + off]; r2[tid] += r2[tid + off]; }
        __syncthreads();
    }
    if (tid == 0) {
        const double ntot  = (double)BC * (double)NVOX;
        double loss1 = r1[0] / ntot;
        double loss2 = r2[0] / ((double)NVOX * (double)(BC * KBINS));
        out[0] = (float)(0.5 * loss1 + 0.5 * loss2);
    }
}

extern "C" void kernel_launch(void* const* d_in, const int* in_sizes, int n_in,
                              void* d_out, int out_size, void* d_ws, size_t ws_size,
                              hipStream_t stream) {
    const float* inp = (const float*)d_in[0];
    const float* tar = (const float*)d_in[1];
    const float* br  = (const float*)d_in[2];

    int*   g_cdf    = (int*)d_ws;
    float* partials = (float*)((char*)d_ws + BC * NEDGE * sizeof(int));

    // CDF accumulators use atomics -> zero every call
    hipMemsetAsync(d_ws, 0, BC * NEDGE * sizeof(int), stream);

    binloss_main<<<NBLOCKS, THREADS, 0, stream>>>(inp, tar, br, g_cdf, partials);
    binloss_final<<<1, 256, 0, stream>>>(g_cdf, partials, (float*)d_out);
}

// Round 6
// 44.732 us; speedup vs baseline: 1.1923x; 1.1923x over previous
//
#include <hip/hip_runtime.h>

#define BC 88                        // B*C channels
#define NVOX 262144                  // 64^3
#define KBINS 20
#define THREADS 256
#define NBLOCKS 2048                 // 8 per CU, fully resident, zero tail
#define CHUNK 1024                   // elements per chunk (256 float4)
#define CPB 11                       // chunks per block: 2048*11*1024 = 23.07M
#define CPC 256                      // chunks per channel: NVOX/CHUNK
#define HSTRIDE 23                   // 22 slots + pad; gcd(23,32)=1
#define NSUB 64                      // per-lane rows shared by 4 waves (atomic)

__global__ void __launch_bounds__(THREADS, 8)
binloss_main(const float* __restrict__ inp, const float* __restrict__ tar,
             const float* __restrict__ br, int* __restrict__ g_hist,
             float* __restrict__ partials)
{
    __shared__ int   rows[NSUB * HSTRIDE];    // 5888 B
    __shared__ float wsum[THREADS / 64];

    const int tid = threadIdx.x;
    for (int i = tid; i < NSUB * HSTRIDE; i += THREADS) rows[i] = 0;

    // uniform scalar loads; +1 folded into shift so (int) truncation == floor
    const float e0     = br[0];
    const float eK     = br[2 * KBINS - 1];
    const float inv_w  = (float)KBINS / (eK - e0);
    const float shift1 = 1.0f - e0 * inv_w;
    const float tmax   = (float)(KBINS + 1) + 0.5f;   // 21.5
    __syncthreads();

    const int fc  = blockIdx.x * CPB;         // first chunk
    const int ch0 = fc >> 8;                  // / CPC
    const int rem = fc & (CPC - 1);
    const int n1  = (rem + CPB > CPC) ? (CPC - rem) : CPB;   // seg-1 chunks

    const float4* ip4 = (const float4*)inp;
    const float4* tp4 = (const float4*)tar;
    int* myrow = &rows[(tid & 63) * HSTRIDE];

    float s_lin = 0.f, s_quad = 0.f;

    // ---- segment 1: chunks [fc, fc+n1), channel ch0 ----
#pragma unroll 2
    for (int c = fc; c < fc + n1; ++c) {
        float4 a = ip4[(size_t)c * 256 + tid];
        float4 b = tp4[(size_t)c * 256 + tid];
#pragma unroll
        for (int q = 0; q < 4; ++q) {
            float av = (&a.x)[q], bv = (&b.x)[q];
            float d = fabsf(av - bv);
            s_lin += fmaxf(d, 1.0f);                       // -1 hoisted out
            float m = fminf(d, 1.0f);
            s_quad  = __builtin_fmaf(m, m, s_quad);
            int sa = (int)__builtin_amdgcn_fmed3f(__builtin_fmaf(av, inv_w, shift1), 0.0f, tmax);
            int sb = (int)__builtin_amdgcn_fmed3f(__builtin_fmaf(bv, inv_w, shift1), 0.0f, tmax);
            atomicAdd(&myrow[sa], 1);                      // slots 0 and 21 = trash
            atomicAdd(&myrow[sb], -1);
        }
    }
    __syncthreads();
    if (tid < 80) {                                        // fold -> channel ch0
        int bin = tid % KBINS, qr = tid / KBINS;
        int s = 0;
#pragma unroll
        for (int r = qr * 16; r < qr * 16 + 16; ++r) s += rows[r * HSTRIDE + 1 + bin];
        atomicAdd(&g_hist[ch0 * KBINS + bin], s);
    }

    // ---- segment 2 (only ~87/2048 blocks): channel ch0+1 ----
    if (n1 < CPB) {
        __syncthreads();
        for (int i = tid; i < NSUB * HSTRIDE; i += THREADS) rows[i] = 0;
        __syncthreads();
#pragma unroll 2
        for (int c = fc + n1; c < fc + CPB; ++c) {
            float4 a = ip4[(size_t)c * 256 + tid];
            float4 b = tp4[(size_t)c * 256 + tid];
#pragma unroll
            for (int q = 0; q < 4; ++q) {
                float av = (&a.x)[q], bv = (&b.x)[q];
                float d = fabsf(av - bv);
                s_lin += fmaxf(d, 1.0f);
                float m = fminf(d, 1.0f);
                s_quad  = __builtin_fmaf(m, m, s_quad);
                int sa = (int)__builtin_amdgcn_fmed3f(__builtin_fmaf(av, inv_w, shift1), 0.0f, tmax);
                int sb = (int)__builtin_amdgcn_fmed3f(__builtin_fmaf(bv, inv_w, shift1), 0.0f, tmax);
                atomicAdd(&myrow[sa], 1);
                atomicAdd(&myrow[sb], -1);
            }
        }
        __syncthreads();
        if (tid < 80) {
            int bin = tid % KBINS, qr = tid / KBINS;
            int s = 0;
#pragma unroll
            for (int r = qr * 16; r < qr * 16 + 16; ++r) s += rows[r * HSTRIDE + 1 + bin];
            atomicAdd(&g_hist[(ch0 + 1) * KBINS + bin], s);
        }
    }

    // SmoothL1 reduce (both segments accumulated in regs)
    float sl1 = (s_lin - (float)(CPB * 4)) + 0.5f * s_quad;
#pragma unroll
    for (int off = 32; off > 0; off >>= 1) sl1 += __shfl_down(sl1, off, 64);
    if ((tid & 63) == 0) wsum[tid >> 6] = sl1;
    __syncthreads();
    if (tid == 0)
        partials[blockIdx.x] = wsum[0] + wsum[1] + wsum[2] + wsum[3];
}

__global__ void __launch_bounds__(256)
binloss_final(const int* __restrict__ g_hist, const float* __restrict__ partials,
              float* __restrict__ out)
{
    __shared__ double r1[256];
    __shared__ double r2[256];
    const int tid = threadIdx.x;
    double s1 = 0.0, s2 = 0.0;
    for (int i = tid; i < NBLOCKS; i += 256) s1 += (double)partials[i];
    for (int i = tid; i < BC * KBINS; i += 256) s2 += fabs((double)g_hist[i]);
    r1[tid] = s1; r2[tid] = s2;
    __syncthreads();
    for (int off = 128; off > 0; off >>= 1) {
        if (tid < off) { r1[tid] += r1[tid + off]; r2[tid] += r2[tid + off]; }
        __syncthreads();
    }
    if (tid == 0) {
        const double ntot  = (double)BC * (double)NVOX;
        double loss1 = r1[0] / ntot;
        double loss2 = r2[0] / ((double)NVOX * (double)(BC * KBINS));
        out[0] = (float)(0.5 * loss1 + 0.5 * loss2);
    }
}

extern "C" void kernel_launch(void* const* d_in, const int* in_sizes, int n_in,
                              void* d_out, int out_size, void* d_ws, size_t ws_size,
                              hipStream_t stream) {
    const float* inp = (const float*)d_in[0];
    const float* tar = (const float*)d_in[1];
    const float* br  = (const float*)d_in[2];

    int*   g_hist   = (int*)d_ws;
    float* partials = (float*)((char*)d_ws + BC * KBINS * sizeof(int));

    // histogram accumulated with atomics -> zero every call
    hipMemsetAsync(d_ws, 0, BC * KBINS * sizeof(int), stream);

    binloss_main<<<NBLOCKS, THREADS, 0, stream>>>(inp, tar, br, g_hist, partials);
    binloss_final<<<1, 256, 0, stream>>>(g_hist, partials, (float*)d_out);
}

// Round 7
// 43.385 us; speedup vs baseline: 1.2293x; 1.0310x over previous
//
#include <hip/hip_runtime.h>

#define BC 88                        // B*C channels
#define NVOX 262144                  // 64^3
#define KBINS 20
#define THREADS 256
#define NBLOCKS 2048                 // 11 chunks per block covers 22528 chunks exactly
#define CPB 11                       // chunks (1024 elems = 256 float4) per block
#define CPC 256                      // chunks per channel
#define HSTRIDE 23                   // 22 slots + pad; gcd(23,32)=1
#define NSUB 64                      // per-lane rows (shared by 4 waves, atomic)
#define ROWSET (NSUB * HSTRIDE)

// R6 inner math (verified absmax 0.0) + deep-batched loads for MLP:
// up to 16 outstanding dwordx4 per wave (vs ~2), __launch_bounds__(256,4)
// gives the 128-VGPR budget to hold them.
__global__ void __launch_bounds__(THREADS, 4)
binloss_main(const float* __restrict__ inp, const float* __restrict__ tar,
             const float* __restrict__ br, int* __restrict__ g_hist,
             float* __restrict__ partials)
{
    __shared__ int   rows[2 * ROWSET];        // two sets: seg-1 / seg-2 channel
    __shared__ float wsum[THREADS / 64];

    const int tid = threadIdx.x;
    for (int i = tid; i < 2 * ROWSET; i += THREADS) rows[i] = 0;

    // uniform scalar loads; +1 folded so (int) truncation == floor
    const float e0     = br[0];
    const float eK     = br[2 * KBINS - 1];
    const float inv_w  = (float)KBINS / (eK - e0);
    const float shift1 = 1.0f - e0 * inv_w;
    const float tmax   = 21.5f;
    __syncthreads();

    const int fc  = blockIdx.x * CPB;
    const int ch0 = fc >> 8;
    const int rem = fc & (CPC - 1);
    const int n1  = (rem + CPB > CPC) ? (CPC - rem) : CPB;   // chunks in channel ch0

    const float4* pa = (const float4*)inp + (size_t)fc * 256 + tid;
    const float4* pb = (const float4*)tar + (size_t)fc * 256 + tid;

    int* r0 = &rows[(tid & 63) * HSTRIDE];
    int* r1 = r0 + ROWSET;

    float s_lin = 0.f, s_quad = 0.f;

    auto proc = [&](float4 a, float4 b, int* rw) {
#pragma unroll
        for (int q = 0; q < 4; ++q) {
            float av = (&a.x)[q], bv = (&b.x)[q];
            float d = fabsf(av - bv);
            s_lin += fmaxf(d, 1.0f);                     // -1 hoisted out
            float m = fminf(d, 1.0f);
            s_quad  = __builtin_fmaf(m, m, s_quad);
            int sa = (int)__builtin_amdgcn_fmed3f(__builtin_fmaf(av, inv_w, shift1), 0.0f, tmax);
            int sb = (int)__builtin_amdgcn_fmed3f(__builtin_fmaf(bv, inv_w, shift1), 0.0f, tmax);
            atomicAdd(&rw[sa], 1);                       // slots 0,21 = trash
            atomicAdd(&rw[sb], -1);
        }
    };

    // ---- batched issue: 16 loads now (k=0..7), 6 more mid-stream ----
    float4 A0 = pa[0 * 256], A1 = pa[1 * 256], A2 = pa[2 * 256], A3 = pa[3 * 256];
    float4 B0 = pb[0 * 256], B1 = pb[1 * 256], B2 = pb[2 * 256], B3 = pb[3 * 256];
    float4 C0 = pa[4 * 256], C1 = pa[5 * 256], C2 = pa[6 * 256], C3 = pa[7 * 256];
    float4 D0 = pb[4 * 256], D1 = pb[5 * 256], D2 = pb[6 * 256], D3 = pb[7 * 256];

    proc(A0, B0, (0 < n1) ? r0 : r1);
    proc(A1, B1, (1 < n1) ? r0 : r1);
    proc(A2, B2, (2 < n1) ? r0 : r1);
    proc(A3, B3, (3 < n1) ? r0 : r1);

    float4 E0 = pa[8 * 256], E1 = pa[9 * 256], E2 = pa[10 * 256];
    float4 F0 = pb[8 * 256], F1 = pb[9 * 256], F2 = pb[10 * 256];

    proc(C0, D0, (4 < n1) ? r0 : r1);
    proc(C1, D1, (5 < n1) ? r0 : r1);
    proc(C2, D2, (6 < n1) ? r0 : r1);
    proc(C3, D3, (7 < n1) ? r0 : r1);
    proc(E0, F0, (8 < n1) ? r0 : r1);
    proc(E1, F1, (9 < n1) ? r0 : r1);
    proc(E2, F2, (10 < n1) ? r0 : r1);

    // SmoothL1 wave(64) + cross-wave reduce
    float sl1 = (s_lin - (float)(CPB * 4)) + 0.5f * s_quad;
#pragma unroll
    for (int off = 32; off > 0; off >>= 1) sl1 += __shfl_down(sl1, off, 64);
    if ((tid & 63) == 0) wsum[tid >> 6] = sl1;
    __syncthreads();

    if (tid == 0)
        partials[blockIdx.x] = wsum[0] + wsum[1] + wsum[2] + wsum[3];

    // fold both row-sets: set 0 -> ch0, set 1 -> ch0+1 (zero unless boundary)
    if (tid < 160) {
        const int set = tid / 80, t2 = tid % 80;
        const int bin = t2 % KBINS, qr = t2 / KBINS;
        const int ch  = ch0 + set;
        if (ch < BC) {
            int s = 0;
#pragma unroll
            for (int r = qr * 16; r < qr * 16 + 16; ++r)
                s += rows[set * ROWSET + r * HSTRIDE + 1 + bin];
            if (s) atomicAdd(&g_hist[ch * KBINS + bin], s);
        }
    }
}

__global__ void __launch_bounds__(256)
binloss_final(const int* __restrict__ g_hist, const float* __restrict__ partials,
              float* __restrict__ out)
{
    __shared__ double r1[256];
    __shared__ double r2[256];
    const int tid = threadIdx.x;
    double s1 = 0.0, s2 = 0.0;
    for (int i = tid; i < NBLOCKS; i += 256) s1 += (double)partials[i];
    for (int i = tid; i < BC * KBINS; i += 256) s2 += fabs((double)g_hist[i]);
    r1[tid] = s1; r2[tid] = s2;
    __syncthreads();
    for (int off = 128; off > 0; off >>= 1) {
        if (tid < off) { r1[tid] += r1[tid + off]; r2[tid] += r2[tid + off]; }
        __syncthreads();
    }
    if (tid == 0) {
        const double ntot  = (double)BC * (double)NVOX;
        double loss1 = r1[0] / ntot;
        double loss2 = r2[0] / ((double)NVOX * (double)(BC * KBINS));
        out[0] = (float)(0.5 * loss1 + 0.5 * loss2);
    }
}

extern "C" void kernel_launch(void* const* d_in, const int* in_sizes, int n_in,
                              void* d_out, int out_size, void* d_ws, size_t ws_size,
                              hipStream_t stream) {
    const float* inp = (const float*)d_in[0];
    const float* tar = (const float*)d_in[1];
    const float* br  = (const float*)d_in[2];

    int*   g_hist   = (int*)d_ws;
    float* partials = (float*)((char*)d_ws + BC * KBINS * sizeof(int));

    // histogram accumulated with atomics -> zero every call
    hipMemsetAsync(d_ws, 0, BC * KBINS * sizeof(int), stream);

    binloss_main<<<NBLOCKS, THREADS, 0, stream>>>(inp, tar, br, g_hist, partials);
    binloss_final<<<1, 256, 0, stream>>>(g_hist, partials, (float*)d_out);
}